// Round 1
// baseline (126.746 us; speedup 1.0000x reference)
//
#include <hip/hip_runtime.h>

#define DIM 8192
#define NLAYERS 8
#define SIMT 512
#define QFB 2048
#define QFT 256
#define ROWS_PER_BLOCK 4

// ---------------------------------------------------------------------------
// Kernel 1: statevector simulation, single workgroup, register-resident state.
// Index layout: flat index i (13 bits). qubit q <-> bit p = 12 - q (row-major
// reshape puts qubit 0 at the MSB). Thread owns 16 amps: i = (tid<<4) | l.
//   bits 0..3  -> local l           (qubits 12..9)
//   bits 4..9  -> lane (tid&63)     (qubits 8..3)
//   bits 10..12-> wave (tid>>6)     (qubits 2..0)
// RX(theta) = [[c, -i s],[-i s, c]], c=cos(th/2), s=sin(th/2); symmetric, so
// a_new = c*a_self - i*s*a_other for either side of the pair:
//   re' = c*re + s*im_other ; im' = c*im - s*re_other
// RZ layer fused into one diagonal phase: phi(i) = sum_q h_q*(2 b_q - 1).
// CNOT chain (q -> q+1 for q=0..11) composes to the permutation
//   j bit p = parity(i bits p..12)  (suffix parity): j = i^(i>>1)^(i>>2)^...
// ---------------------------------------------------------------------------
__global__ __launch_bounds__(SIMT) void sim_kernel(const float* __restrict__ params,
                                                   float* __restrict__ outR,
                                                   float* __restrict__ outM) {
    __shared__ float2 lds[DIM];   // exactly 64 KB
    const int tid = threadIdx.x;

    float2 a[16];
#pragma unroll
    for (int l = 0; l < 16; ++l) a[l] = make_float2(0.f, 0.f);
    if (tid == 0) a[0].x = 1.f;

    for (int layer = 0; layer < NLAYERS; ++layer) {
        const int pb = layer * 26;

        // ---- RX on local bits p=0..3 (qubits 12..9): in-register pairs ----
#pragma unroll
        for (int p = 0; p < 4; ++p) {
            float c, s;
            __sincosf(0.5f * params[pb + (12 - p)], &s, &c);
#pragma unroll
            for (int l0 = 0; l0 < 16; ++l0) {
                if (!(l0 & (1 << p))) {
                    const int l1 = l0 | (1 << p);
                    const float2 a0 = a[l0], a1 = a[l1];
                    a[l0] = make_float2(fmaf(c, a0.x, s * a1.y), fmaf(c, a0.y, -s * a1.x));
                    a[l1] = make_float2(fmaf(c, a1.x, s * a0.y), fmaf(c, a1.y, -s * a0.x));
                }
            }
        }

        // ---- RX on lane bits p=4..9 (qubits 8..3): shfl_xor within wave ----
#pragma unroll
        for (int p = 4; p < 10; ++p) {
            float c, s;
            __sincosf(0.5f * params[pb + (12 - p)], &s, &c);
            const int mask = 1 << (p - 4);
#pragma unroll
            for (int l = 0; l < 16; ++l) {
                const float ox = __shfl_xor(a[l].x, mask);
                const float oy = __shfl_xor(a[l].y, mask);
                a[l] = make_float2(fmaf(c, a[l].x, s * oy), fmaf(c, a[l].y, -s * ox));
            }
        }

        // ---- RX on wave bits p=10..12 (qubits 2..0): LDS exchange ----
#pragma unroll
        for (int p = 10; p < 13; ++p) {
            float c, s;
            __sincosf(0.5f * params[pb + (12 - p)], &s, &c);
            const int pt = tid ^ (1 << (p - 4));
            __syncthreads();   // protect against previous phase's LDS reads
#pragma unroll
            for (int l = 0; l < 16; ++l) lds[l * SIMT + tid] = a[l];
            __syncthreads();
#pragma unroll
            for (int l = 0; l < 16; ++l) {
                const float2 o = lds[l * SIMT + pt];
                a[l] = make_float2(fmaf(c, a[l].x, s * o.y), fmaf(c, a[l].y, -s * o.x));
            }
        }

        // ---- RZ layer, fused diagonal ----
        // qubit q (0..8) lives at tid bit (8-q); qubits 9..12 at l bits 3..0
        float phi_hi = 0.f;
#pragma unroll
        for (int q = 0; q <= 8; ++q) {
            const float h = 0.5f * params[pb + 13 + q];
            phi_hi += ((tid >> (8 - q)) & 1) ? h : -h;
        }
        const float h9  = 0.5f * params[pb + 13 + 9];
        const float h10 = 0.5f * params[pb + 13 + 10];
        const float h11 = 0.5f * params[pb + 13 + 11];
        const float h12 = 0.5f * params[pb + 13 + 12];
#pragma unroll
        for (int l = 0; l < 16; ++l) {
            float phi = phi_hi;
            phi += (l & 8) ? h9  : -h9;   // qubit 9  at bit 3
            phi += (l & 4) ? h10 : -h10;  // qubit 10 at bit 2
            phi += (l & 2) ? h11 : -h11;  // qubit 11 at bit 1
            phi += (l & 1) ? h12 : -h12;  // qubit 12 at bit 0
            float sp, cp;
            __sincosf(phi, &sp, &cp);
            a[l] = make_float2(a[l].x * cp - a[l].y * sp, a[l].x * sp + a[l].y * cp);
        }

        // ---- CNOT chain: one LDS scatter permutation ----
        __syncthreads();
#pragma unroll
        for (int l = 0; l < 16; ++l) {
            const int i = (tid << 4) | l;
            int j = i;
            j ^= j >> 1; j ^= j >> 2; j ^= j >> 4; j ^= j >> 8;
            lds[j] = a[l];
        }
        __syncthreads();
#pragma unroll
        for (int l = 0; l < 16; ++l) a[l] = lds[(tid << 4) | l];
    }

    // ---- write r = Re(psi), m = Im(psi), vectorized float4 stores ----
    const int base4 = tid << 2;   // float4 index base (tid*16 floats /4)
#pragma unroll
    for (int g = 0; g < 4; ++g) {
        const float4 rv = make_float4(a[4*g].x, a[4*g+1].x, a[4*g+2].x, a[4*g+3].x);
        const float4 mv = make_float4(a[4*g].y, a[4*g+1].y, a[4*g+2].y, a[4*g+3].y);
        ((float4*)outR)[base4 + g] = rv;
        ((float4*)outM)[base4 + g] = mv;
    }
}

// ---------------------------------------------------------------------------
// Kernel 2: loss = r^T O r + m^T O m, one streaming pass over O (memory-bound).
// Each block handles 4 consecutive rows; per-block partial sum (deterministic).
// ---------------------------------------------------------------------------
__global__ __launch_bounds__(QFT) void quad_kernel(const float* __restrict__ O,
                                                   const float* __restrict__ R,
                                                   const float* __restrict__ M,
                                                   float* __restrict__ partials) {
    const int bi = blockIdx.x;
    const int t  = threadIdx.x;
    const float4* __restrict__ R4 = (const float4*)R;
    const float4* __restrict__ M4 = (const float4*)M;

    float acc = 0.f;
#pragma unroll
    for (int rr = 0; rr < ROWS_PER_BLOCK; ++rr) {
        const int i = bi * ROWS_PER_BLOCK + rr;
        const float ri = R[i];
        const float mi = M[i];
        const float4* __restrict__ Or = (const float4*)(O + (size_t)i * DIM);
#pragma unroll
        for (int it = 0; it < DIM / 4 / QFT; ++it) {   // 8 iterations
            const int j4 = t + it * QFT;
            const float4 o  = Or[j4];
            const float4 rj = R4[j4];
            const float4 mj = M4[j4];
            acc = fmaf(o.x, fmaf(ri, rj.x, mi * mj.x), acc);
            acc = fmaf(o.y, fmaf(ri, rj.y, mi * mj.y), acc);
            acc = fmaf(o.z, fmaf(ri, rj.z, mi * mj.z), acc);
            acc = fmaf(o.w, fmaf(ri, rj.w, mi * mj.w), acc);
        }
    }

    // block reduction: wave shuffle then LDS across the 4 waves
#pragma unroll
    for (int off = 32; off > 0; off >>= 1) acc += __shfl_down(acc, off);
    __shared__ float wsum[QFT / 64];
    const int lane = t & 63, w = t >> 6;
    if (lane == 0) wsum[w] = acc;
    __syncthreads();
    if (t == 0) {
        float s = 0.f;
#pragma unroll
        for (int k = 0; k < QFT / 64; ++k) s += wsum[k];
        partials[bi] = s;
    }
}

// ---------------------------------------------------------------------------
// Kernel 3: sum the 2048 per-block partials into the scalar output.
// ---------------------------------------------------------------------------
__global__ __launch_bounds__(256) void reduce_kernel(const float* __restrict__ partials,
                                                     float* __restrict__ out) {
    const int t = threadIdx.x;
    float acc = 0.f;
#pragma unroll
    for (int k = 0; k < QFB / 256; ++k) acc += partials[t + k * 256];
#pragma unroll
    for (int off = 32; off > 0; off >>= 1) acc += __shfl_down(acc, off);
    __shared__ float wsum[4];
    const int lane = t & 63, w = t >> 6;
    if (lane == 0) wsum[w] = acc;
    __syncthreads();
    if (t == 0) out[0] = wsum[0] + wsum[1] + wsum[2] + wsum[3];
}

extern "C" void kernel_launch(void* const* d_in, const int* in_sizes, int n_in,
                              void* d_out, int out_size, void* d_ws, size_t ws_size,
                              hipStream_t stream) {
    const float* params = (const float*)d_in[0];   // 208 fp32
    const float* O      = (const float*)d_in[1];   // 8192*8192 fp32
    float* out = (float*)d_out;                    // 1 fp32

    float* R        = (float*)d_ws;       // 8192 floats
    float* M        = R + DIM;            // 8192 floats
    float* partials = M + DIM;            // QFB floats

    sim_kernel<<<1, SIMT, 0, stream>>>(params, R, M);
    quad_kernel<<<QFB, QFT, 0, stream>>>(O, R, M, partials);
    reduce_kernel<<<1, 256, 0, stream>>>(partials, out);
}

// Round 3
// 83.992 us; speedup vs baseline: 1.5090x; 1.5090x over previous
//
#include <hip/hip_runtime.h>

#define DIM 8192
#define NLAYERS 8
#define SIMT 512        // sim threads: 8 waves, 16 amps/thread
#define QFB 2048
#define QFT 256
#define ROWS_PER_BLOCK 4

typedef float floatx4 __attribute__((ext_vector_type(4)));

// ---------------------------------------------------------------------------
// Statevector sim, single workgroup. qubit q <-> bit p = 12-q of flat index.
// All RX gates are register-local via layout cycling:
//   canonical C: i = (t<<4)|l          (l = bits 0-3)
//   layout   A: i = (t&15)|(l<<4)|((t>>4)<<8)   (l = bits 4-7)
//   layout   B: i = ((t>>1)&255)|(l<<8)|((t&1)<<12)  (l = bits 8-11, bit12 = lane bit 0)
// Per layer: RX(bits0-3) -> R1 transpose -> RX(4-7) -> R2 transpose ->
//            RX(8-11) + RX(bit12 via shfl_xor 1) -> RZ diag -> R3 = CNOT round
// CNOT chain == suffix-parity perm j_p = XOR_{k>=p} i_k ; inverse i = j^(j>>1).
// R3 gather-reads canonical, so layout is restored for the next layer.
// LDS: ping-pong 2x64KB, ONE barrier per round (3/layer).
// Swizzle swz(i)=i^((i>>4)&15): all six access patterns are even 4-way
// (the b64 minimum for 64 lanes x 32 banks) -- verified by GF(2) analysis.
// ---------------------------------------------------------------------------
__device__ __forceinline__ int swz(int i) { return i ^ ((i >> 4) & 15); }

__global__ __launch_bounds__(SIMT) void sim_kernel(const float* __restrict__ params,
                                                   float* __restrict__ outR,
                                                   float* __restrict__ outM) {
    __shared__ float2 buf[2][DIM];   // 128 KiB ping-pong
    const int t = threadIdx.x;

    float2 a[16];
#pragma unroll
    for (int l = 0; l < 16; ++l) a[l] = make_float2(0.f, 0.f);
    if (t == 0) a[0].x = 1.f;

    int pp = 0;  // ping-pong parity

    for (int layer = 0; layer < NLAYERS; ++layer) {
        const float* __restrict__ prx = params + layer * 26;
        const float* __restrict__ prz = prx + 13;

        // RX cos/sin per BIT p (qubit 12-p), uniform across threads
        float cb[13], sb[13];
#pragma unroll
        for (int p = 0; p < 13; ++p) __sincosf(0.5f * prx[12 - p], &sb[p], &cb[p]);

        // ---- RX group 0: i-bits 0..3 == l-bits 0..3 ----
#pragma unroll
        for (int k = 0; k < 4; ++k) {
            const float c = cb[k], s = sb[k];
#pragma unroll
            for (int l0 = 0; l0 < 16; ++l0) {
                if (!(l0 & (1 << k))) {
                    const int l1 = l0 | (1 << k);
                    const float2 a0 = a[l0], a1 = a[l1];
                    a[l0] = make_float2(fmaf(c, a0.x, s * a1.y), fmaf(c, a0.y, -s * a1.x));
                    a[l1] = make_float2(fmaf(c, a1.x, s * a0.y), fmaf(c, a1.y, -s * a0.x));
                }
            }
        }

        // ---- R1: canonical -> layout A ----
        {
            float2* __restrict__ B = buf[pp]; pp ^= 1;
#pragma unroll
            for (int l = 0; l < 16; ++l) B[swz((t << 4) | l)] = a[l];
            __syncthreads();
#pragma unroll
            for (int l = 0; l < 16; ++l) a[l] = B[swz((t & 15) | (l << 4) | ((t >> 4) << 8))];
        }

        // ---- RX group 1: i-bits 4..7 == l-bits 0..3 (layout A) ----
#pragma unroll
        for (int k = 0; k < 4; ++k) {
            const float c = cb[4 + k], s = sb[4 + k];
#pragma unroll
            for (int l0 = 0; l0 < 16; ++l0) {
                if (!(l0 & (1 << k))) {
                    const int l1 = l0 | (1 << k);
                    const float2 a0 = a[l0], a1 = a[l1];
                    a[l0] = make_float2(fmaf(c, a0.x, s * a1.y), fmaf(c, a0.y, -s * a1.x));
                    a[l1] = make_float2(fmaf(c, a1.x, s * a0.y), fmaf(c, a1.y, -s * a0.x));
                }
            }
        }

        // ---- R2: layout A -> layout B ----
        {
            float2* __restrict__ B = buf[pp]; pp ^= 1;
#pragma unroll
            for (int l = 0; l < 16; ++l) B[swz((t & 15) | (l << 4) | ((t >> 4) << 8))] = a[l];
            __syncthreads();
#pragma unroll
            for (int l = 0; l < 16; ++l)
                a[l] = B[swz(((t >> 1) & 255) | (l << 8) | ((t & 1) << 12))];
        }

        // ---- RX group 2: i-bits 8..11 == l-bits 0..3 (layout B) ----
#pragma unroll
        for (int k = 0; k < 4; ++k) {
            const float c = cb[8 + k], s = sb[8 + k];
#pragma unroll
            for (int l0 = 0; l0 < 16; ++l0) {
                if (!(l0 & (1 << k))) {
                    const int l1 = l0 | (1 << k);
                    const float2 a0 = a[l0], a1 = a[l1];
                    a[l0] = make_float2(fmaf(c, a0.x, s * a1.y), fmaf(c, a0.y, -s * a1.x));
                    a[l1] = make_float2(fmaf(c, a1.x, s * a0.y), fmaf(c, a1.y, -s * a0.x));
                }
            }
        }

        // ---- RX on bit 12 (qubit 0): lane bit 0 -> shfl_xor 1 ----
        {
            const float c = cb[12], s = sb[12];
#pragma unroll
            for (int l = 0; l < 16; ++l) {
                const float ox = __shfl_xor(a[l].x, 1);
                const float oy = __shfl_xor(a[l].y, 1);
                a[l] = make_float2(fmaf(c, a[l].x, s * oy), fmaf(c, a[l].y, -s * ox));
            }
        }

        // ---- RZ diagonal (layout B): phase +h if bit set, h indexed by bit p ----
        float hz[13];
#pragma unroll
        for (int p = 0; p < 13; ++p) hz[p] = 0.5f * prz[12 - p];
        float phiT = 0.f;
#pragma unroll
        for (int p = 0; p < 8; ++p) phiT += (((t >> 1) >> p) & 1) ? hz[p] : -hz[p];
        phiT += (t & 1) ? hz[12] : -hz[12];
#pragma unroll
        for (int l = 0; l < 16; ++l) {
            float phi = phiT;
            phi += (l & 1) ? hz[8]  : -hz[8];
            phi += (l & 2) ? hz[9]  : -hz[9];
            phi += (l & 4) ? hz[10] : -hz[10];
            phi += (l & 8) ? hz[11] : -hz[11];
            float sp, cp;
            __sincosf(phi, &sp, &cp);
            a[l] = make_float2(a[l].x * cp - a[l].y * sp, a[l].x * sp + a[l].y * cp);
        }

        // ---- R3: CNOT round, layout B -> canonical via inverse perm gather ----
        {
            float2* __restrict__ B = buf[pp]; pp ^= 1;
#pragma unroll
            for (int l = 0; l < 16; ++l)
                B[swz(((t >> 1) & 255) | (l << 8) | ((t & 1) << 12))] = a[l];
            __syncthreads();
#pragma unroll
            for (int l = 0; l < 16; ++l) {
                const int c0 = (t << 4) | l;
                a[l] = B[swz(c0 ^ (c0 >> 1))];
            }
        }
    }

    // ---- write r, m as float4 (canonical: i = t*16 + l, contiguous) ----
#pragma unroll
    for (int g = 0; g < 4; ++g) {
        const float4 rv = make_float4(a[4*g].x, a[4*g+1].x, a[4*g+2].x, a[4*g+3].x);
        const float4 mv = make_float4(a[4*g].y, a[4*g+1].y, a[4*g+2].y, a[4*g+3].y);
        ((float4*)outR)[(t << 2) + g] = rv;
        ((float4*)outM)[(t << 2) + g] = mv;
    }
}

// ---------------------------------------------------------------------------
// loss = r^T O r + m^T O m : one streaming pass over O (memory-bound).
// Nontemporal loads on O (zero reuse); R/M served from L1/L2.
// ---------------------------------------------------------------------------
__global__ __launch_bounds__(QFT) void quad_kernel(const float* __restrict__ O,
                                                   const float* __restrict__ R,
                                                   const float* __restrict__ M,
                                                   float* __restrict__ partials) {
    const int bi = blockIdx.x;
    const int t  = threadIdx.x;
    const float4* __restrict__ R4 = (const float4*)R;
    const float4* __restrict__ M4 = (const float4*)M;

    float acc = 0.f;
#pragma unroll
    for (int rr = 0; rr < ROWS_PER_BLOCK; ++rr) {
        const int i = bi * ROWS_PER_BLOCK + rr;
        const float ri = R[i];
        const float mi = M[i];
        const floatx4* __restrict__ Or = (const floatx4*)(O + (size_t)i * DIM);
#pragma unroll
        for (int it = 0; it < DIM / 4 / QFT; ++it) {   // 8 iterations
            const int j4 = t + it * QFT;
            const floatx4 o = __builtin_nontemporal_load(&Or[j4]);
            const float4 rj = R4[j4];
            const float4 mj = M4[j4];
            acc = fmaf(o.x, fmaf(ri, rj.x, mi * mj.x), acc);
            acc = fmaf(o.y, fmaf(ri, rj.y, mi * mj.y), acc);
            acc = fmaf(o.z, fmaf(ri, rj.z, mi * mj.z), acc);
            acc = fmaf(o.w, fmaf(ri, rj.w, mi * mj.w), acc);
        }
    }

#pragma unroll
    for (int off = 32; off > 0; off >>= 1) acc += __shfl_down(acc, off);
    __shared__ float wsum[QFT / 64];
    const int lane = t & 63, w = t >> 6;
    if (lane == 0) wsum[w] = acc;
    __syncthreads();
    if (t == 0) {
        float s = 0.f;
#pragma unroll
        for (int k = 0; k < QFT / 64; ++k) s += wsum[k];
        partials[bi] = s;
    }
}

__global__ __launch_bounds__(256) void reduce_kernel(const float* __restrict__ partials,
                                                     float* __restrict__ out) {
    const int t = threadIdx.x;
    float acc = 0.f;
#pragma unroll
    for (int k = 0; k < QFB / 256; ++k) acc += partials[t + k * 256];
#pragma unroll
    for (int off = 32; off > 0; off >>= 1) acc += __shfl_down(acc, off);
    __shared__ float wsum[4];
    const int lane = t & 63, w = t >> 6;
    if (lane == 0) wsum[w] = acc;
    __syncthreads();
    if (t == 0) out[0] = wsum[0] + wsum[1] + wsum[2] + wsum[3];
}

extern "C" void kernel_launch(void* const* d_in, const int* in_sizes, int n_in,
                              void* d_out, int out_size, void* d_ws, size_t ws_size,
                              hipStream_t stream) {
    const float* params = (const float*)d_in[0];   // 208 fp32
    const float* O      = (const float*)d_in[1];   // 8192*8192 fp32
    float* out = (float*)d_out;

    float* R        = (float*)d_ws;
    float* M        = R + DIM;
    float* partials = M + DIM;

    sim_kernel<<<1, SIMT, 0, stream>>>(params, R, M);
    quad_kernel<<<QFB, QFT, 0, stream>>>(O, R, M, partials);
    reduce_kernel<<<1, 256, 0, stream>>>(partials, out);
}